// Round 10
// baseline (211.377 us; speedup 1.0000x reference)
//
#include <hip/hip_runtime.h>
#include <stdint.h>

#define B_ 8
#define T_ 1024
#define C_ 768
#define H_ 12
#define DK 64
#define BT (B_*T_)      // 8192
#define NQKV (3*C_)     // 2304

typedef unsigned short u16;
typedef __bf16 bf16x8 __attribute__((ext_vector_type(8)));
typedef __bf16 bf16x4 __attribute__((ext_vector_type(4)));
typedef float  f32x4  __attribute__((ext_vector_type(4)));

typedef const __attribute__((address_space(1))) void gvoid_t;
typedef __attribute__((address_space(3))) void lvoid_t;

// Raw s_barrier is NOT a compiler fence (LLVM IntrNoMem) — caused R6's replay
// race. asm volatile + "memory" clobber = compiler-only fence, zero extra
// instructions, preserves fine-grained vmcnt pipelining.
#define SBARRIER()  asm volatile("s_barrier" ::: "memory")
#define SWAITCNT(s) asm volatile("s_waitcnt " s ::: "memory")

__device__ __forceinline__ void gl_lds16(const void* g, void* l) {
    __builtin_amdgcn_global_load_lds((gvoid_t*)g, (lvoid_t*)l, 16, 0, 0);
}

__device__ __forceinline__ u16 f2b(float f) {
    union { float f; unsigned int u; } v; v.f = f;
    unsigned int u = v.u;
    return (u16)((u + 0x7fffu + ((u >> 16) & 1u)) >> 16);
}

__device__ __forceinline__ f32x4 mfma16(bf16x8 a, bf16x8 b, f32x4 c) {
    return __builtin_amdgcn_mfma_f32_16x16x32_bf16(a, b, c, 0, 0, 0);
}

// ---------- merged prep: convert x + transpose both W (one launch) ----------
// blocks [0,6144): x f32->bf16 x4          (6144*256*4 = 6.29M elems)
// blocks [6144,7872): Wqkv^T 72x24 tiles
// blocks [7872,8448): Wout^T 24x24 tiles
__global__ __launch_bounds__(256)
void k_prep(const float* __restrict__ x, u16* __restrict__ xb,
            const float* __restrict__ wqkv, u16* __restrict__ wqkvT,
            const float* __restrict__ wout, u16* __restrict__ woutT)
{
    __shared__ u16 tile[32][34];
    const int bid = blockIdx.x;
    const int tid = threadIdx.x;
    if (bid < 6144) {
        int i = bid * 256 + tid;
        float4 f = ((const float4*)x)[i];
        uint2 o;
        o.x = (unsigned)f2b(f.x) | ((unsigned)f2b(f.y) << 16);
        o.y = (unsigned)f2b(f.z) | ((unsigned)f2b(f.w) << 16);
        ((uint2*)xb)[i] = o;
        return;
    }
    const float* w; u16* wt; int K, N, n0, k0;
    if (bid < 6144 + 1728) {
        int idx = bid - 6144;
        w = wqkv; wt = wqkvT; K = C_; N = NQKV;
        n0 = (idx % 72) * 32; k0 = (idx / 72) * 32;
    } else {
        int idx = bid - 7872;
        w = wout; wt = woutT; K = C_; N = C_;
        n0 = (idx % 24) * 32; k0 = (idx / 24) * 32;
    }
    const int tx = tid & 31, ty = tid >> 5;   // 32 x 8
    #pragma unroll
    for (int i = 0; i < 4; i++)
        tile[ty + i * 8][tx] = f2b(w[(size_t)(k0 + ty + i * 8) * N + n0 + tx]);
    __syncthreads();
    #pragma unroll
    for (int i = 0; i < 4; i++)
        wt[(size_t)(n0 + ty + i * 8) * K + k0 + tx] = tile[tx][ty + i * 8];
}

// ---------- QKV GEMM: 128 x (3x96) A-reuse tile, BK=32, 3-stage dist-2 ----------
// R15/R7: A-tile staged once for all three qkv sections (3x output area);
// 512 blocks = one round at 2/CU. Measured 51.7us (from 60.3). KEEP.
__global__ __launch_bounds__(256, 2)
void k_gemm_qkv(const u16* __restrict__ A, const u16* __restrict__ Bt,
                const float* __restrict__ bias,
                u16* __restrict__ qo, u16* __restrict__ ko, u16* __restrict__ vto)
{
    const int K = C_;
    __shared__ u16 As[3][128 * 32];   // 3 x 8 KB
    __shared__ u16 Bs[3][288 * 32];   // 3 x 18 KB  (78 KB total -> 2 blocks/CU)
    const int tid  = threadIdx.x;
    const int lane = tid & 63;
    const int w    = tid >> 6;
    const int quad = lane >> 4;
    const int col  = lane & 15;

    const int id   = blockIdx.x + gridDim.x * blockIdx.y;  // grid (8, 64) = 512
    const int xcd  = id & 7;
    const int slot = id >> 3;             // 0..63
    const int m0   = (xcd * 8 + (slot & 7)) * 128;   // 64 m-tiles
    const int n0   = (slot >> 3) * 96;               // 8 n-groups (96 cols/section)

    const int wm   = w * 32;              // 4 waves stacked in M

    f32x4 zero4 = {0.f, 0.f, 0.f, 0.f};
    f32x4 acc[2][18];
    #pragma unroll
    for (int i = 0; i < 2; i++)
        #pragma unroll
        for (int j = 0; j < 18; j++) acc[i][j] = zero4;

    const int sr  = tid >> 2;             // 0..63
    const int scc = ((tid & 3) ^ ((sr >> 1) & 3)) * 8;
    const u16* gA = A  + (size_t)(m0 + sr) * K + scc;
    const u16* gB = Bt + (size_t)(n0 + sr) * K + scc;   // +s*768*K per section

    const int NIT = K >> 5;   // 24

    // A: rows 0-63 + 64-127 (2 all-wave loads). B per section s (LDS rows
    // s*96..s*96+95): rows 0-63 all waves; rows 64-95 waves 0,1 (their sr in
    // 0..31 -> gB + 64*K). Section LDS base = s*96*32*2 = s*6144 bytes.
    #define STAGE(kt, bufi)                                                               \
        do {                                                                              \
            gl_lds16(gA + (kt),                  (char*)As[bufi] + w * 1024);             \
            gl_lds16(gA + (size_t)64 * K + (kt), (char*)As[bufi] + 4096 + w * 1024);      \
            _Pragma("unroll")                                                             \
            for (int s = 0; s < 3; s++) {                                                 \
                const u16* gBs = gB + (size_t)(s * C_) * K;                               \
                gl_lds16(gBs + (kt), (char*)Bs[bufi] + s * 6144 + w * 1024);              \
                if (w < 2)                                                                \
                    gl_lds16(gBs + (size_t)64 * K + (kt),                                 \
                             (char*)Bs[bufi] + s * 6144 + 4096 + w * 1024);               \
            }                                                                             \
        } while (0)

    STAGE(0, 0);
    STAGE(32, 1);
    int cur = 0;
    for (int it = 0; it < NIT; ++it) {
        // drain OWN tile-it loads (issued at it-2); tile it+1's stay in flight
        if (it + 1 < NIT) {
            if (w < 2) { SWAITCNT("vmcnt(8)"); } else { SWAITCNT("vmcnt(5)"); }
        } else {
            SWAITCNT("vmcnt(0)");
        }
        SBARRIER();    // joint: RAW(tile it landed) + WAR(tile it-1 readers done)
        if (it + 2 < NIT) {
            int b2 = cur + 2; if (b2 >= 3) b2 -= 3;
            STAGE((it + 2) << 5, b2);      // into tile it-1's buffer: WAR-safe
        }

        const u16* Ab = As[cur];
        const u16* Bb = Bs[cur];
        bf16x8 af[2];
        #pragma unroll
        for (int mt = 0; mt < 2; mt++) {
            int row = wm + mt * 16 + col;
            af[mt] = *(const bf16x8*)&Ab[row * 32 + ((quad ^ ((row >> 1) & 3)) * 8)];
        }
        #pragma unroll
        for (int nt = 0; nt < 18; nt++) {
            int row = nt * 16 + col;
            bf16x8 bfr = *(const bf16x8*)&Bb[row * 32 + ((quad ^ ((row >> 1) & 3)) * 8)];
            acc[0][nt] = mfma16(af[0], bfr, acc[0][nt]);
            acc[1][nt] = mfma16(af[1], bfr, acc[1][nt]);
        }

        cur = (cur == 2) ? 0 : cur + 1;
    }
    #undef STAGE

    // epilogue: nt 0-5 -> q, 6-11 -> k, 12-17 -> v (96 cols each, 16-aligned)
    #pragma unroll
    for (int mt = 0; mt < 2; mt++) {
        #pragma unroll
        for (int nt = 0; nt < 18; nt++) {
            const int sec = nt / 6;
            const int cc  = n0 + (nt - sec * 6) * 16 + col;   // 0..767
            const int h   = cc >> 6;
            const int d   = cc & 63;
            #pragma unroll
            for (int r = 0; r < 4; r++) {
                int m = m0 + wm + mt * 16 + quad * 4 + r;
                int b = m >> 10;
                int t = m & 1023;
                int bh = b * H_ + h;
                float v = acc[mt][nt][r] + bias[sec * C_ + cc];
                u16 bv = f2b(v);
                if (sec == 0)      qo [((size_t)bh * T_ + t) * DK + d] = bv;
                else if (sec == 1) ko [((size_t)bh * T_ + t) * DK + d] = bv;
                else               vto[((size_t)bh * DK + d) * T_ + t] = bv;
            }
        }
    }
}

// ---------- out-proj GEMM: 128x96, BK=64, 2-buffer, single barrier/iter ----------
// R16: R5-proven structure ported; 512 blocks at 2/CU = one balanced round.
// Measured R8: total -3.1us. KEEP.
__global__ __launch_bounds__(256, 2)
void k_gemm_out(const u16* __restrict__ A, const u16* __restrict__ Bt,
                const float* __restrict__ bias, float* __restrict__ outf)
{
    const int K = C_, N = C_;
    __shared__ u16 As[2][2][128 * 32];   // [buf][sub]  2 x 16 KB
    __shared__ u16 Bs[2][2][96 * 32];    // [buf][sub]  2 x 12 KB  (56 KB total)
    const int tid  = threadIdx.x;
    const int lane = tid & 63;
    const int w    = tid >> 6;
    const int quad = lane >> 4;
    const int col  = lane & 15;

    const int id   = blockIdx.x;          // 0..511
    const int xcd  = id & 7;
    const int slot = id >> 3;             // 0..63
    const int m0   = (xcd * 8 + (slot & 7)) * 128;   // 64 m-tiles
    const int n0   = (slot >> 3) * 96;               // 8 n-tiles

    const int wm   = w * 32;              // 4 waves stacked in M

    f32x4 zero4 = {0.f, 0.f, 0.f, 0.f};
    f32x4 acc[2][6];
    #pragma unroll
    for (int i = 0; i < 2; i++)
        #pragma unroll
        for (int j = 0; j < 6; j++) acc[i][j] = zero4;

    const int sr  = tid >> 2;             // 0..63
    const int scc = ((tid & 3) ^ ((sr >> 1) & 3)) * 8;
    const u16* gA = A  + (size_t)(m0 + sr) * K + scc;
    const u16* gB = Bt + (size_t)(n0 + sr) * K + scc;

    const int NT64 = K >> 6;   // 12 K-tiles of 64

    // One BK=32 sub-stage: A rows 0-63 + 64-127 (2 all-wave loads); B rows
    // 0-63 (all waves) + rows 64-95 (waves 0,1: their sr in 0..31 -> +64).
    #define SUB(kt, bufi, subi)                                                           \
        do {                                                                              \
            gl_lds16(gA + (kt),                  (char*)As[bufi][subi] + w * 1024);       \
            gl_lds16(gA + (size_t)64 * K + (kt), (char*)As[bufi][subi] + 4096 + w * 1024);\
            gl_lds16(gB + (kt),                  (char*)Bs[bufi][subi] + w * 1024);       \
            if (w < 2)                                                                    \
                gl_lds16(gB + (size_t)64 * K + (kt), (char*)Bs[bufi][subi] + 4096 + w * 1024);\
        } while (0)
    #define STAGE(t, bufi)  do { SUB(((t) << 6), bufi, 0); SUB(((t) << 6) + 32, bufi, 1); } while (0)

    STAGE(0, 0);
    for (int it = 0; it < NT64; ++it) {
        const int cur = it & 1;
        SWAITCNT("vmcnt(0)");   // drain own tile-it loads (issued iter it-1)
        SBARRIER();             // joint: RAW(tile it landed) + WAR(tile it-1 readers done)
        if (it + 1 < NT64)
            STAGE(it + 1, cur ^ 1);   // into tile it-1's buffer: WAR-safe

        #pragma unroll
        for (int kk = 0; kk < 2; ++kk) {
            const u16* Ab = As[cur][kk];
            const u16* Bb = Bs[cur][kk];
            bf16x8 af[2], bfr[6];
            #pragma unroll
            for (int mt = 0; mt < 2; mt++) {
                int row = wm + mt * 16 + col;
                af[mt] = *(const bf16x8*)&Ab[row * 32 + ((quad ^ ((row >> 1) & 3)) * 8)];
            }
            #pragma unroll
            for (int nt = 0; nt < 6; nt++) {
                int row = nt * 16 + col;
                bfr[nt] = *(const bf16x8*)&Bb[row * 32 + ((quad ^ ((row >> 1) & 3)) * 8)];
            }
            #pragma unroll
            for (int mt = 0; mt < 2; mt++)
                #pragma unroll
                for (int nt = 0; nt < 6; nt++)
                    acc[mt][nt] = mfma16(af[mt], bfr[nt], acc[mt][nt]);
        }
    }
    #undef STAGE
    #undef SUB

    #pragma unroll
    for (int mt = 0; mt < 2; mt++) {
        #pragma unroll
        for (int nt = 0; nt < 6; nt++) {
            #pragma unroll
            for (int r = 0; r < 4; r++) {
                int m = m0 + wm + mt * 16 + quad * 4 + r;
                int n = n0 + nt * 16 + col;
                outf[(size_t)m * N + n] = acc[mt][nt][r] + bias[n];
            }
        }
    }
}

// ---------- causal flash attention: NO K/V LDS staging (L2-direct) ----------
// R18: R9's dist-2 port was a wash (latency cover == residency loss) -> attn
// is not staging-latency-bound; the LDS round-trip itself is the overhead
// (guide m169: dropping V-staging when K/V L2-fits was +26%). Per-bh K/V =
// 256 KB; 12 bh/XCD = 3 MB < 4 MB L2 (id%8 XCD round-robin keeps bh+8k on
// one XCD). Fragments read DIRECTLY from global (swizzle algebra: LDS path's
// logical content = K[kv0+g*16+col][{0,32}+quad*8..+8] and
// V^T[dt*16+col][kv0+{0,32}+quad*8..+8], both 16B-aligned per-lane loads).
// Kernel is now BARRIER-FREE: waves fully independent, only the wave-local
// lgkmcnt(0) for the P LDS round-trip remains. LDS 66->18 KB.
#define PSTRIDE 72   // u16 elems; 144B rows

template <bool MASK>
__device__ __forceinline__ void attn_chunk(
    const u16* __restrict__ Kb, const u16* __restrict__ Vb, __bf16* pbuf,
    const bf16x8 (&qf)[2][2], bf16x8 ones,
    int kv0, int qw, int quad, int col,
    f32x4 (&oacc)[2][4], f32x4 (&lacc)[2])
{
    f32x4 zero4 = {0.f, 0.f, 0.f, 0.f};
    f32x4 st[2][4];
    #pragma unroll
    for (int g = 0; g < 4; g++) {
        const u16* kp = Kb + (size_t)(kv0 + g * 16 + col) * DK + quad * 8;
        bf16x8 klo = *(const bf16x8*)(kp);
        bf16x8 khi = *(const bf16x8*)(kp + 32);
        st[0][g] = mfma16(khi, qf[0][1], mfma16(klo, qf[0][0], zero4));
        st[1][g] = mfma16(khi, qf[1][1], mfma16(klo, qf[1][0], zero4));
    }
    const float scl = 0.18033688f;   // log2(e)/8
    #pragma unroll
    for (int s = 0; s < 2; s++) {
        __bf16* pb = pbuf + s * 16 * PSTRIDE + col * PSTRIDE;
        #pragma unroll
        for (int g = 0; g < 4; g++) {
            bf16x4 pp;
            #pragma unroll
            for (int r = 0; r < 4; r++) {
                float p = __builtin_amdgcn_exp2f(st[s][g][r] * scl - 12.0f);
                if (MASK) {
                    int kv = kv0 + g * 16 + quad * 4 + r;
                    if (kv > qw + s * 16 + col) p = 0.f;
                }
                pp[r] = (__bf16)p;
            }
            *(bf16x4*)(pb + g * 16 + quad * 4) = pp;
        }
    }
    SWAITCNT("lgkmcnt(0)");   // wave-local LDS ordering for P round-trip
    bf16x8 pf[2][2];
    #pragma unroll
    for (int s = 0; s < 2; s++) {
        const __bf16* pb = pbuf + s * 16 * PSTRIDE + col * PSTRIDE;
        pf[s][0] = *(const bf16x8*)(pb + quad * 8);
        pf[s][1] = *(const bf16x8*)(pb + 32 + quad * 8);
        lacc[s] = mfma16(pf[s][1], ones, mfma16(pf[s][0], ones, lacc[s]));
    }
    #pragma unroll
    for (int dt = 0; dt < 4; dt++) {
        const u16* vp = Vb + (size_t)(dt * 16 + col) * T_ + kv0 + quad * 8;
        bf16x8 vlo = *(const bf16x8*)(vp);
        bf16x8 vhi = *(const bf16x8*)(vp + 32);
        #pragma unroll
        for (int s = 0; s < 2; s++)
            oacc[s][dt] = mfma16(pf[s][1], vhi, mfma16(pf[s][0], vlo, oacc[s][dt]));
    }
}

__global__ __launch_bounds__(256, 3)
void k_attn(const u16* __restrict__ Q, const u16* __restrict__ Kf,
            const u16* __restrict__ Vt, u16* __restrict__ Of)
{
    __shared__ __bf16 Plds[4][32 * PSTRIDE];   // 18 KB only
    const int bh   = blockIdx.x;
    const int b    = bh / H_;
    const int h    = bh - b * H_;
    const int tid  = threadIdx.x;
    const int lane = tid & 63;
    const int w    = tid >> 6;
    const int quad = lane >> 4;
    const int col  = lane & 15;
    const int ty   = 7 - (int)blockIdx.y;
    const int nch  = 2 * ty + 2;
    const int qw   = ty * 128 + w * 32;
    __bf16* pbuf = Plds[w];

    const u16* Qb = Q  + (size_t)bh * T_ * DK;
    const u16* Kb = Kf + (size_t)bh * T_ * DK;
    const u16* Vb = Vt + (size_t)bh * DK * T_;

    bf16x8 qf[2][2];
    #pragma unroll
    for (int s = 0; s < 2; s++) {
        const u16* qp = Qb + (size_t)(qw + s * 16 + col) * DK;
        qf[s][0] = *(const bf16x8*)(qp + quad * 8);
        qf[s][1] = *(const bf16x8*)(qp + 32 + quad * 8);
    }

    bf16x8 ones;
    #pragma unroll
    for (int i = 0; i < 8; i++) ((u16*)&ones)[i] = 0x3F80;

    f32x4 zero4 = {0.f, 0.f, 0.f, 0.f};
    f32x4 oacc[2][4];
    f32x4 lacc[2] = {zero4, zero4};
    #pragma unroll
    for (int s = 0; s < 2; s++)
        #pragma unroll
        for (int dt = 0; dt < 4; dt++) oacc[s][dt] = zero4;

    #pragma unroll 1
    for (int c = 0; c < nch; ++c) {
        const int kv0 = c * 64;
        if (kv0 <= qw + 31) {
            if (kv0 + 63 <= qw)
                attn_chunk<false>(Kb, Vb, pbuf, qf, ones, kv0, qw, quad, col, oacc, lacc);
            else
                attn_chunk<true>(Kb, Vb, pbuf, qf, ones, kv0, qw, quad, col, oacc, lacc);
        }
    }

    #pragma unroll
    for (int s = 0; s < 2; s++) {
        #pragma unroll
        for (int r = 0; r < 4; r++) {
            float inv = 1.f / lacc[s][r];
            int t = qw + s * 16 + quad * 4 + r;
            u16* op = Of + ((size_t)(b * T_ + t)) * C_ + h * DK;
            #pragma unroll
            for (int dt = 0; dt < 4; dt++) op[dt * 16 + col] = f2b(oacc[s][dt][r] * inv);
        }
    }
}

extern "C" void kernel_launch(void* const* d_in, const int* in_sizes, int n_in,
                              void* d_out, int out_size, void* d_ws, size_t ws_size,
                              hipStream_t stream) {
    const float* x    = (const float*)d_in[0];
    const float* Wqkv = (const float*)d_in[1];
    const float* bqkv = (const float*)d_in[2];
    const float* Wout = (const float*)d_in[3];
    const float* bout = (const float*)d_in[4];
    float* out = (float*)d_out;

    char* ws = (char*)d_ws;
    u16* xb    = (u16*)(ws);                    // 8192*768     bf16 = 12.0 MiB
    u16* wqkvT = (u16*)(ws + 12582912);         // [2304,768]   bf16
    u16* woutT = (u16*)(ws + 16121856);         // [768,768]    bf16
    u16* qw    = (u16*)(ws + 17301504);         // [96,1024,64] bf16
    u16* kw    = (u16*)(ws + 29884416);         // [96,1024,64] bf16
    u16* vtw   = (u16*)(ws + 42467328);         // [96,64,1024] bf16
    u16* aw    = (u16*)(ws + 55050240);         // [8192,768]   bf16  (end ~67.6 MB)

    k_prep<<<8448, 256, 0, stream>>>(x, xb, Wqkv, wqkvT, Wout, woutT);

    k_gemm_qkv<<<dim3(8, BT / 128), 256, 0, stream>>>(
        xb, wqkvT, bqkv, qw, kw, vtw);

    k_attn<<<dim3(B_ * H_, 8), 256, 0, stream>>>(qw, kw, vtw, aw);

    k_gemm_out<<<512, 256, 0, stream>>>(aw, woutT, bout, out);
}

// Round 11
// 177.488 us; speedup vs baseline: 1.1909x; 1.1909x over previous
//
#include <hip/hip_runtime.h>
#include <stdint.h>

#define B_ 8
#define T_ 1024
#define C_ 768
#define H_ 12
#define DK 64
#define BT (B_*T_)      // 8192
#define NQKV (3*C_)     // 2304

typedef unsigned short u16;
typedef __bf16 bf16x8 __attribute__((ext_vector_type(8)));
typedef __bf16 bf16x4 __attribute__((ext_vector_type(4)));
typedef float  f32x4  __attribute__((ext_vector_type(4)));

typedef const __attribute__((address_space(1))) void gvoid_t;
typedef __attribute__((address_space(3))) void lvoid_t;

// Raw s_barrier is NOT a compiler fence (LLVM IntrNoMem) — caused R6's replay
// race. asm volatile + "memory" clobber = compiler-only fence, zero extra
// instructions, preserves fine-grained vmcnt pipelining.
#define SBARRIER()  asm volatile("s_barrier" ::: "memory")
#define SWAITCNT(s) asm volatile("s_waitcnt " s ::: "memory")

__device__ __forceinline__ void gl_lds16(const void* g, void* l) {
    __builtin_amdgcn_global_load_lds((gvoid_t*)g, (lvoid_t*)l, 16, 0, 0);
}

__device__ __forceinline__ u16 f2b(float f) {
    union { float f; unsigned int u; } v; v.f = f;
    unsigned int u = v.u;
    return (u16)((u + 0x7fffu + ((u >> 16) & 1u)) >> 16);
}

__device__ __forceinline__ f32x4 mfma16(bf16x8 a, bf16x8 b, f32x4 c) {
    return __builtin_amdgcn_mfma_f32_16x16x32_bf16(a, b, c, 0, 0, 0);
}

// ---------- merged prep: convert x + transpose both W (one launch) ----------
__global__ __launch_bounds__(256)
void k_prep(const float* __restrict__ x, u16* __restrict__ xb,
            const float* __restrict__ wqkv, u16* __restrict__ wqkvT,
            const float* __restrict__ wout, u16* __restrict__ woutT)
{
    __shared__ u16 tile[32][34];
    const int bid = blockIdx.x;
    const int tid = threadIdx.x;
    if (bid < 6144) {
        int i = bid * 256 + tid;
        float4 f = ((const float4*)x)[i];
        uint2 o;
        o.x = (unsigned)f2b(f.x) | ((unsigned)f2b(f.y) << 16);
        o.y = (unsigned)f2b(f.z) | ((unsigned)f2b(f.w) << 16);
        ((uint2*)xb)[i] = o;
        return;
    }
    const float* w; u16* wt; int K, N, n0, k0;
    if (bid < 6144 + 1728) {
        int idx = bid - 6144;
        w = wqkv; wt = wqkvT; K = C_; N = NQKV;
        n0 = (idx % 72) * 32; k0 = (idx / 72) * 32;
    } else {
        int idx = bid - 7872;
        w = wout; wt = woutT; K = C_; N = C_;
        n0 = (idx % 24) * 32; k0 = (idx / 24) * 32;
    }
    const int tx = tid & 31, ty = tid >> 5;   // 32 x 8
    #pragma unroll
    for (int i = 0; i < 4; i++)
        tile[ty + i * 8][tx] = f2b(w[(size_t)(k0 + ty + i * 8) * N + n0 + tx]);
    __syncthreads();
    #pragma unroll
    for (int i = 0; i < 4; i++)
        wt[(size_t)(n0 + ty + i * 8) * K + k0 + tx] = tile[tx][ty + i * 8];
}

// ---------- QKV GEMM: 256 x (3x96) A-reuse tile, 512 thr, BK=32, dist-2 ----------
// R19: R10's L2-direct attn regressed (attn 68us — gl_lds pipelining, not
// LDS-bypass, was the value); attn reverted to R8. This round: qkv staged-
// bytes lever again. BM=128->256 at same A-reuse tile: staged 327->214 MB,
// grid = 32x8 = 256 blocks = ONE round at 1 block/CU (102 KB LDS, 512 thr =
// 8 waves in M). Inner loop = R7's proven BK=32/3-stage/dist-2/merged-
// barrier, re-ledgered for 512 threads: A = 2 all-thread loads (rows 0-127,
// 128-255); B section s = 1 load by waves 0-5 (sr<96). Per-wave issues/stage:
// w<6: 2A+3B=5, w>=6: 2A=2 -> steady pre-barrier vmcnt(5)/(2), final vmcnt(0).
// dist-2 = ~2 iteration-times of latency cover at 1 block/CU.
__global__ __launch_bounds__(512, 1)
void k_gemm_qkv(const u16* __restrict__ A, const u16* __restrict__ Bt,
                const float* __restrict__ bias,
                u16* __restrict__ qo, u16* __restrict__ ko, u16* __restrict__ vto)
{
    const int K = C_;
    __shared__ u16 As[3][256 * 32];   // 3 x 16 KB
    __shared__ u16 Bs[3][288 * 32];   // 3 x 18 KB  (102 KB total -> 1 block/CU)
    const int tid  = threadIdx.x;
    const int lane = tid & 63;
    const int w    = tid >> 6;        // 0..7
    const int quad = lane >> 4;
    const int col  = lane & 15;

    const int id   = blockIdx.x;      // 0..255
    const int xcd  = id & 7;
    const int slot = id >> 3;         // 0..31
    const int m0   = (xcd * 4 + (slot & 3)) * 256;   // 32 m-tiles
    const int n0   = (slot >> 2) * 96;               // 8 n-groups

    const int wm   = w * 32;          // 8 waves stacked in M

    f32x4 zero4 = {0.f, 0.f, 0.f, 0.f};
    f32x4 acc[2][18];
    #pragma unroll
    for (int i = 0; i < 2; i++)
        #pragma unroll
        for (int j = 0; j < 18; j++) acc[i][j] = zero4;

    const int sr  = tid >> 2;         // 0..127
    const int scc = ((tid & 3) ^ ((sr >> 1) & 3)) * 8;
    const u16* gA = A  + (size_t)(m0 + sr) * K + scc;
    const u16* gB = Bt + (size_t)(n0 + sr) * K + scc;   // used only by sr<96

    const int NIT = K >> 5;   // 24

    // A: rows 0-127, 128-255 (two all-thread loads, 8KB each). B per section
    // s (LDS rows s*96..+95 = s*6144 B): rows 0-95 by threads sr<96 (w<6).
    #define STAGE(kt, bufi)                                                               \
        do {                                                                              \
            gl_lds16(gA + (kt),                   (char*)As[bufi] + w * 1024);            \
            gl_lds16(gA + (size_t)128 * K + (kt), (char*)As[bufi] + 8192 + w * 1024);     \
            if (w < 6) {                                                                  \
                _Pragma("unroll")                                                         \
                for (int s = 0; s < 3; s++)                                               \
                    gl_lds16(gB + (size_t)(s * C_) * K + (kt),                            \
                             (char*)Bs[bufi] + s * 6144 + w * 1024);                      \
            }                                                                             \
        } while (0)

    STAGE(0, 0);
    STAGE(32, 1);
    int cur = 0;
    for (int it = 0; it < NIT; ++it) {
        // drain OWN tile-it loads (issued at it-2); tile it+1's stay in flight
        if (it + 1 < NIT) {
            if (w < 6) { SWAITCNT("vmcnt(5)"); } else { SWAITCNT("vmcnt(2)"); }
        } else {
            SWAITCNT("vmcnt(0)");
        }
        SBARRIER();    // joint: RAW(tile it landed) + WAR(tile it-1 readers done)
        if (it + 2 < NIT) {
            int b2 = cur + 2; if (b2 >= 3) b2 -= 3;
            STAGE((it + 2) << 5, b2);      // into tile it-1's buffer: WAR-safe
        }

        const u16* Ab = As[cur];
        const u16* Bb = Bs[cur];
        bf16x8 af[2];
        #pragma unroll
        for (int mt = 0; mt < 2; mt++) {
            int row = wm + mt * 16 + col;
            af[mt] = *(const bf16x8*)&Ab[row * 32 + ((quad ^ ((row >> 1) & 3)) * 8)];
        }
        #pragma unroll
        for (int nt = 0; nt < 18; nt++) {
            int row = nt * 16 + col;
            bf16x8 bfr = *(const bf16x8*)&Bb[row * 32 + ((quad ^ ((row >> 1) & 3)) * 8)];
            acc[0][nt] = mfma16(af[0], bfr, acc[0][nt]);
            acc[1][nt] = mfma16(af[1], bfr, acc[1][nt]);
        }

        cur = (cur == 2) ? 0 : cur + 1;
    }
    #undef STAGE

    // epilogue: nt 0-5 -> q, 6-11 -> k, 12-17 -> v (96 cols each, 16-aligned)
    #pragma unroll
    for (int mt = 0; mt < 2; mt++) {
        #pragma unroll
        for (int nt = 0; nt < 18; nt++) {
            const int sec = nt / 6;
            const int cc  = n0 + (nt - sec * 6) * 16 + col;   // 0..767
            const int h   = cc >> 6;
            const int d   = cc & 63;
            #pragma unroll
            for (int r = 0; r < 4; r++) {
                int m = m0 + wm + mt * 16 + quad * 4 + r;
                int b = m >> 10;
                int t = m & 1023;
                int bh = b * H_ + h;
                float v = acc[mt][nt][r] + bias[sec * C_ + cc];
                u16 bv = f2b(v);
                if (sec == 0)      qo [((size_t)bh * T_ + t) * DK + d] = bv;
                else if (sec == 1) ko [((size_t)bh * T_ + t) * DK + d] = bv;
                else               vto[((size_t)bh * DK + d) * T_ + t] = bv;
            }
        }
    }
}

// ---------- out-proj GEMM: 128x96, BK=64, 2-buffer, single barrier/iter ----------
// R16: R5-proven structure ported; 512 blocks at 2/CU = one balanced round.
// Measured R8: total -3.1us. KEEP.
__global__ __launch_bounds__(256, 2)
void k_gemm_out(const u16* __restrict__ A, const u16* __restrict__ Bt,
                const float* __restrict__ bias, float* __restrict__ outf)
{
    const int K = C_, N = C_;
    __shared__ u16 As[2][2][128 * 32];   // [buf][sub]  2 x 16 KB
    __shared__ u16 Bs[2][2][96 * 32];    // [buf][sub]  2 x 12 KB  (56 KB total)
    const int tid  = threadIdx.x;
    const int lane = tid & 63;
    const int w    = tid >> 6;
    const int quad = lane >> 4;
    const int col  = lane & 15;

    const int id   = blockIdx.x;          // 0..511
    const int xcd  = id & 7;
    const int slot = id >> 3;             // 0..63
    const int m0   = (xcd * 8 + (slot & 7)) * 128;   // 64 m-tiles
    const int n0   = (slot >> 3) * 96;               // 8 n-tiles

    const int wm   = w * 32;              // 4 waves stacked in M

    f32x4 zero4 = {0.f, 0.f, 0.f, 0.f};
    f32x4 acc[2][6];
    #pragma unroll
    for (int i = 0; i < 2; i++)
        #pragma unroll
        for (int j = 0; j < 6; j++) acc[i][j] = zero4;

    const int sr  = tid >> 2;             // 0..63
    const int scc = ((tid & 3) ^ ((sr >> 1) & 3)) * 8;
    const u16* gA = A  + (size_t)(m0 + sr) * K + scc;
    const u16* gB = Bt + (size_t)(n0 + sr) * K + scc;

    const int NT64 = K >> 6;   // 12 K-tiles of 64

    #define SUB(kt, bufi, subi)                                                           \
        do {                                                                              \
            gl_lds16(gA + (kt),                  (char*)As[bufi][subi] + w * 1024);       \
            gl_lds16(gA + (size_t)64 * K + (kt), (char*)As[bufi][subi] + 4096 + w * 1024);\
            gl_lds16(gB + (kt),                  (char*)Bs[bufi][subi] + w * 1024);       \
            if (w < 2)                                                                    \
                gl_lds16(gB + (size_t)64 * K + (kt), (char*)Bs[bufi][subi] + 4096 + w * 1024);\
        } while (0)
    #define STAGE(t, bufi)  do { SUB(((t) << 6), bufi, 0); SUB(((t) << 6) + 32, bufi, 1); } while (0)

    STAGE(0, 0);
    for (int it = 0; it < NT64; ++it) {
        const int cur = it & 1;
        SWAITCNT("vmcnt(0)");   // drain own tile-it loads (issued iter it-1)
        SBARRIER();             // joint: RAW(tile it landed) + WAR(tile it-1 readers done)
        if (it + 1 < NT64)
            STAGE(it + 1, cur ^ 1);   // into tile it-1's buffer: WAR-safe

        #pragma unroll
        for (int kk = 0; kk < 2; ++kk) {
            const u16* Ab = As[cur][kk];
            const u16* Bb = Bs[cur][kk];
            bf16x8 af[2], bfr[6];
            #pragma unroll
            for (int mt = 0; mt < 2; mt++) {
                int row = wm + mt * 16 + col;
                af[mt] = *(const bf16x8*)&Ab[row * 32 + ((quad ^ ((row >> 1) & 3)) * 8)];
            }
            #pragma unroll
            for (int nt = 0; nt < 6; nt++) {
                int row = nt * 16 + col;
                bfr[nt] = *(const bf16x8*)&Bb[row * 32 + ((quad ^ ((row >> 1) & 3)) * 8)];
            }
            #pragma unroll
            for (int mt = 0; mt < 2; mt++)
                #pragma unroll
                for (int nt = 0; nt < 6; nt++)
                    acc[mt][nt] = mfma16(af[mt], bfr[nt], acc[mt][nt]);
        }
    }
    #undef STAGE
    #undef SUB

    #pragma unroll
    for (int mt = 0; mt < 2; mt++) {
        #pragma unroll
        for (int nt = 0; nt < 6; nt++) {
            #pragma unroll
            for (int r = 0; r < 4; r++) {
                int m = m0 + wm + mt * 16 + quad * 4 + r;
                int n = n0 + nt * 16 + col;
                outf[(size_t)m * N + n] = acc[mt][nt][r] + bias[n];
            }
        }
    }
}

// ---------- causal flash attention: R8 version (dist-1 dbuf, single barrier) ----------
// R18 lesson: L2-direct (no staging) regressed 68us — the gl_lds pipeline's
// decoupled issue/consume IS the value, not just the LDS cache. Reverted.
#define PSTRIDE 72   // u16 elems; 144B rows

__device__ __forceinline__ bf16x8 ld_sw(const u16* base, int row, int half,
                                        int quad, int c7) {
    return *(const bf16x8*)(base + row * DK + (((half * 4 + quad) ^ c7) * 8));
}

template <bool MASK>
__device__ __forceinline__ void attn_chunk(
    const u16* Ks, const u16* Vs, __bf16* pbuf,
    const bf16x8 (&qf)[2][2], bf16x8 ones,
    int kv0, int qw, int quad, int col,
    f32x4 (&oacc)[2][4], f32x4 (&lacc)[2])
{
    const int c7 = col & 7;
    f32x4 zero4 = {0.f, 0.f, 0.f, 0.f};
    f32x4 st[2][4];
    #pragma unroll
    for (int g = 0; g < 4; g++) {
        bf16x8 klo = ld_sw(Ks, g * 16 + col, 0, quad, c7);
        bf16x8 khi = ld_sw(Ks, g * 16 + col, 1, quad, c7);
        st[0][g] = mfma16(khi, qf[0][1], mfma16(klo, qf[0][0], zero4));
        st[1][g] = mfma16(khi, qf[1][1], mfma16(klo, qf[1][0], zero4));
    }
    const float scl = 0.18033688f;   // log2(e)/8
    #pragma unroll
    for (int s = 0; s < 2; s++) {
        __bf16* pb = pbuf + s * 16 * PSTRIDE + col * PSTRIDE;
        #pragma unroll
        for (int g = 0; g < 4; g++) {
            bf16x4 pp;
            #pragma unroll
            for (int r = 0; r < 4; r++) {
                float p = __builtin_amdgcn_exp2f(st[s][g][r] * scl - 12.0f);
                if (MASK) {
                    int kv = kv0 + g * 16 + quad * 4 + r;
                    if (kv > qw + s * 16 + col) p = 0.f;
                }
                pp[r] = (__bf16)p;
            }
            *(bf16x4*)(pb + g * 16 + quad * 4) = pp;
        }
    }
    SWAITCNT("lgkmcnt(0)");   // wave-local LDS ordering for P round-trip
    bf16x8 pf[2][2];
    #pragma unroll
    for (int s = 0; s < 2; s++) {
        const __bf16* pb = pbuf + s * 16 * PSTRIDE + col * PSTRIDE;
        pf[s][0] = *(const bf16x8*)(pb + quad * 8);
        pf[s][1] = *(const bf16x8*)(pb + 32 + quad * 8);
        lacc[s] = mfma16(pf[s][1], ones, mfma16(pf[s][0], ones, lacc[s]));
    }
    #pragma unroll
    for (int dt = 0; dt < 4; dt++) {
        bf16x8 vlo = ld_sw(Vs, dt * 16 + col, 0, quad, c7);
        bf16x8 vhi = ld_sw(Vs, dt * 16 + col, 1, quad, c7);
        #pragma unroll
        for (int s = 0; s < 2; s++)
            oacc[s][dt] = mfma16(pf[s][1], vhi, mfma16(pf[s][0], vlo, oacc[s][dt]));
    }
}

__global__ __launch_bounds__(256, 3)
void k_attn(const u16* __restrict__ Q, const u16* __restrict__ Kf,
            const u16* __restrict__ Vt, u16* __restrict__ Of)
{
    __shared__ u16 Ks[2][64 * DK];
    __shared__ u16 Vs[2][64 * DK];
    __shared__ __bf16 Plds[4][32 * PSTRIDE];
    const int bh   = blockIdx.x;
    const int b    = bh / H_;
    const int h    = bh - b * H_;
    const int tid  = threadIdx.x;
    const int lane = tid & 63;
    const int w    = tid >> 6;
    const int quad = lane >> 4;
    const int col  = lane & 15;
    const int ty   = 7 - (int)blockIdx.y;
    const int nch  = 2 * ty + 2;
    const int qw   = ty * 128 + w * 32;
    __bf16* pbuf = Plds[w];

    const u16* Qb = Q  + (size_t)bh * T_ * DK;
    const u16* Kb = Kf + (size_t)bh * T_ * DK;
    const u16* Vb = Vt + (size_t)bh * DK * T_;

    int sG0 = tid, sG1 = 256 + tid;
    int sr0 = sG0 >> 3, sg0 = (sG0 & 7) ^ (sr0 & 7);
    int sr1 = sG1 >> 3, sg1 = (sG1 & 7) ^ (sr1 & 7);

    bf16x8 qf[2][2];
    #pragma unroll
    for (int s = 0; s < 2; s++) {
        const u16* qp = Qb + (size_t)(qw + s * 16 + col) * DK;
        qf[s][0] = *(const bf16x8*)(qp + quad * 8);
        qf[s][1] = *(const bf16x8*)(qp + 32 + quad * 8);
    }

    bf16x8 ones;
    #pragma unroll
    for (int i = 0; i < 8; i++) ((u16*)&ones)[i] = 0x3F80;

    f32x4 zero4 = {0.f, 0.f, 0.f, 0.f};
    f32x4 oacc[2][4];
    f32x4 lacc[2] = {zero4, zero4};
    #pragma unroll
    for (int s = 0; s < 2; s++)
        #pragma unroll
        for (int dt = 0; dt < 4; dt++) oacc[s][dt] = zero4;

    #define ASTAGE(c, bufi)                                                            \
        do {                                                                           \
            int kvs = (c) * 64;                                                        \
            gl_lds16(Kb + (size_t)(kvs + sr0) * DK + sg0 * 8, (char*)Ks[bufi] + w * 1024);        \
            gl_lds16(Kb + (size_t)(kvs + sr1) * DK + sg1 * 8, (char*)Ks[bufi] + 4096 + w * 1024); \
            gl_lds16(Vb + (size_t)sr0 * T_ + kvs + sg0 * 8,   (char*)Vs[bufi] + w * 1024);        \
            gl_lds16(Vb + (size_t)sr1 * T_ + kvs + sg1 * 8,   (char*)Vs[bufi] + 4096 + w * 1024); \
        } while (0)

    ASTAGE(0, 0);
    #pragma unroll 1
    for (int c = 0; c < nch; ++c) {
        const int cur = c & 1;
        SWAITCNT("vmcnt(0)");              // own chunk-c loads drained (issued last chunk)
        SBARRIER();                        // joint: chunk c landed + buf[!cur] readers done
        if (c + 1 < nch) {
            ASTAGE(c + 1, cur ^ 1);        // WAR-safe post-barrier
        }

        const int kv0 = c * 64;
        if (kv0 <= qw + 31) {
            if (kv0 + 63 <= qw)
                attn_chunk<false>(Ks[cur], Vs[cur], pbuf, qf, ones, kv0, qw, quad, col, oacc, lacc);
            else
                attn_chunk<true>(Ks[cur], Vs[cur], pbuf, qf, ones, kv0, qw, quad, col, oacc, lacc);
        }
    }
    #undef ASTAGE

    #pragma unroll
    for (int s = 0; s < 2; s++) {
        #pragma unroll
        for (int r = 0; r < 4; r++) {
            float inv = 1.f / lacc[s][r];
            int t = qw + s * 16 + quad * 4 + r;
            u16* op = Of + ((size_t)(b * T_ + t)) * C_ + h * DK;
            #pragma unroll
            for (int dt = 0; dt < 4; dt++) op[dt * 16 + col] = f2b(oacc[s][dt][r] * inv);
        }
    }
}

extern "C" void kernel_launch(void* const* d_in, const int* in_sizes, int n_in,
                              void* d_out, int out_size, void* d_ws, size_t ws_size,
                              hipStream_t stream) {
    const float* x    = (const float*)d_in[0];
    const float* Wqkv = (const float*)d_in[1];
    const float* bqkv = (const float*)d_in[2];
    const float* Wout = (const float*)d_in[3];
    const float* bout = (const float*)d_in[4];
    float* out = (float*)d_out;

    char* ws = (char*)d_ws;
    u16* xb    = (u16*)(ws);                    // 8192*768     bf16 = 12.0 MiB
    u16* wqkvT = (u16*)(ws + 12582912);         // [2304,768]   bf16
    u16* woutT = (u16*)(ws + 16121856);         // [768,768]    bf16
    u16* qw    = (u16*)(ws + 17301504);         // [96,1024,64] bf16
    u16* kw    = (u16*)(ws + 29884416);         // [96,1024,64] bf16
    u16* vtw   = (u16*)(ws + 42467328);         // [96,64,1024] bf16
    u16* aw    = (u16*)(ws + 55050240);         // [8192,768]   bf16  (end ~67.6 MB)

    k_prep<<<8448, 256, 0, stream>>>(x, xb, Wqkv, wqkvT, Wout, woutT);

    k_gemm_qkv<<<256, 512, 0, stream>>>(
        xb, wqkvT, bqkv, qw, kw, vtw);

    k_attn<<<dim3(B_ * H_, 8), 256, 0, stream>>>(qw, kw, vtw, aw);

    k_gemm_out<<<512, 256, 0, stream>>>(aw, woutT, bout, out);
}

// Round 13
// 172.972 us; speedup vs baseline: 1.2220x; 1.0261x over previous
//
#include <hip/hip_runtime.h>
#include <stdint.h>

#define B_ 8
#define T_ 1024
#define C_ 768
#define H_ 12
#define DK 64
#define BT (B_*T_)      // 8192
#define NQKV (3*C_)     // 2304

typedef unsigned short u16;
typedef __bf16 bf16x8 __attribute__((ext_vector_type(8)));
typedef __bf16 bf16x4 __attribute__((ext_vector_type(4)));
typedef float  f32x4  __attribute__((ext_vector_type(4)));

typedef const __attribute__((address_space(1))) void gvoid_t;
typedef __attribute__((address_space(3))) void lvoid_t;

// Raw s_barrier is NOT a compiler fence (LLVM IntrNoMem) — caused R6's replay
// race. asm volatile + "memory" clobber = compiler-only fence, zero extra
// instructions, preserves fine-grained vmcnt pipelining.
#define SBARRIER()  asm volatile("s_barrier" ::: "memory")
#define SWAITCNT(s) asm volatile("s_waitcnt " s ::: "memory")

__device__ __forceinline__ void gl_lds16(const void* g, void* l) {
    __builtin_amdgcn_global_load_lds((gvoid_t*)g, (lvoid_t*)l, 16, 0, 0);
}

__device__ __forceinline__ u16 f2b(float f) {
    union { float f; unsigned int u; } v; v.f = f;
    unsigned int u = v.u;
    return (u16)((u + 0x7fffu + ((u >> 16) & 1u)) >> 16);
}

__device__ __forceinline__ f32x4 mfma16(bf16x8 a, bf16x8 b, f32x4 c) {
    return __builtin_amdgcn_mfma_f32_16x16x32_bf16(a, b, c, 0, 0, 0);
}

// ---------- merged prep: convert x + transpose both W (one launch) ----------
__global__ __launch_bounds__(256)
void k_prep(const float* __restrict__ x, u16* __restrict__ xb,
            const float* __restrict__ wqkv, u16* __restrict__ wqkvT,
            const float* __restrict__ wout, u16* __restrict__ woutT)
{
    __shared__ u16 tile[32][34];
    const int bid = blockIdx.x;
    const int tid = threadIdx.x;
    if (bid < 6144) {
        int i = bid * 256 + tid;
        float4 f = ((const float4*)x)[i];
        uint2 o;
        o.x = (unsigned)f2b(f.x) | ((unsigned)f2b(f.y) << 16);
        o.y = (unsigned)f2b(f.z) | ((unsigned)f2b(f.w) << 16);
        ((uint2*)xb)[i] = o;
        return;
    }
    const float* w; u16* wt; int K, N, n0, k0;
    if (bid < 6144 + 1728) {
        int idx = bid - 6144;
        w = wqkv; wt = wqkvT; K = C_; N = NQKV;
        n0 = (idx % 72) * 32; k0 = (idx / 72) * 32;
    } else {
        int idx = bid - 7872;
        w = wout; wt = woutT; K = C_; N = C_;
        n0 = (idx % 24) * 32; k0 = (idx / 24) * 32;
    }
    const int tx = tid & 31, ty = tid >> 5;   // 32 x 8
    #pragma unroll
    for (int i = 0; i < 4; i++)
        tile[ty + i * 8][tx] = f2b(w[(size_t)(k0 + ty + i * 8) * N + n0 + tx]);
    __syncthreads();
    #pragma unroll
    for (int i = 0; i < 4; i++)
        wt[(size_t)(n0 + ty + i * 8) * K + k0 + tx] = tile[tx][ty + i * 8];
}

// ---------- QKV GEMM: 128 x (3x96) A-reuse tile, BK=32, 3-stage dist-2 ----------
// R15/R7: A-tile staged once for all three qkv sections (3x output area);
// 512 blocks = one round at 2/CU. Measured 51.7us. KEEP structure.
// R20/R21: WRITE_SIZE 52 MB vs 37.7 ideal — the vto scatter (~2x sector
// amplification). Fix: v-section transposed through LDS (reuse Bs) ->
// coalesced bf16x8 stores. R12's refcheck failure was the transpose READ
// side covering only t in [tch, tch+8) of each 16-step (half of vto stale).
// Fixed: 6 passes x 16 rows, tch = (tid&15)*8 covers all 128 t.
__global__ __launch_bounds__(256, 2)
void k_gemm_qkv(const u16* __restrict__ A, const u16* __restrict__ Bt,
                const float* __restrict__ bias,
                u16* __restrict__ qo, u16* __restrict__ ko, u16* __restrict__ vto)
{
    const int K = C_;
    __shared__ u16 As[3][128 * 32];   // 3 x 8 KB
    __shared__ u16 Bs[3][288 * 32];   // 3 x 18 KB  (78 KB total -> 2 blocks/CU)
    const int tid  = threadIdx.x;
    const int lane = tid & 63;
    const int w    = tid >> 6;
    const int quad = lane >> 4;
    const int col  = lane & 15;

    const int id   = blockIdx.x + gridDim.x * blockIdx.y;  // grid (8, 64) = 512
    const int xcd  = id & 7;
    const int slot = id >> 3;             // 0..63
    const int m0   = (xcd * 8 + (slot & 7)) * 128;   // 64 m-tiles
    const int n0   = (slot >> 3) * 96;               // 8 n-groups (96 cols/section)

    const int wm   = w * 32;              // 4 waves stacked in M

    f32x4 zero4 = {0.f, 0.f, 0.f, 0.f};
    f32x4 acc[2][18];
    #pragma unroll
    for (int i = 0; i < 2; i++)
        #pragma unroll
        for (int j = 0; j < 18; j++) acc[i][j] = zero4;

    const int sr  = tid >> 2;             // 0..63
    const int scc = ((tid & 3) ^ ((sr >> 1) & 3)) * 8;
    const u16* gA = A  + (size_t)(m0 + sr) * K + scc;
    const u16* gB = Bt + (size_t)(n0 + sr) * K + scc;   // +s*768*K per section

    const int NIT = K >> 5;   // 24

    // A: rows 0-63 + 64-127 (2 all-wave loads). B per section s (LDS rows
    // s*96..s*96+95): rows 0-63 all waves; rows 64-95 waves 0,1 (their sr in
    // 0..31 -> gB + 64*K). Section LDS base = s*96*32*2 = s*6144 bytes.
    #define STAGE(kt, bufi)                                                               \
        do {                                                                              \
            gl_lds16(gA + (kt),                  (char*)As[bufi] + w * 1024);             \
            gl_lds16(gA + (size_t)64 * K + (kt), (char*)As[bufi] + 4096 + w * 1024);      \
            _Pragma("unroll")                                                             \
            for (int s = 0; s < 3; s++) {                                                 \
                const u16* gBs = gB + (size_t)(s * C_) * K;                               \
                gl_lds16(gBs + (kt), (char*)Bs[bufi] + s * 6144 + w * 1024);              \
                if (w < 2)                                                                \
                    gl_lds16(gBs + (size_t)64 * K + (kt),                                 \
                             (char*)Bs[bufi] + s * 6144 + 4096 + w * 1024);               \
            }                                                                             \
        } while (0)

    STAGE(0, 0);
    STAGE(32, 1);
    int cur = 0;
    for (int it = 0; it < NIT; ++it) {
        // drain OWN tile-it loads (issued at it-2); tile it+1's stay in flight
        if (it + 1 < NIT) {
            if (w < 2) { SWAITCNT("vmcnt(8)"); } else { SWAITCNT("vmcnt(5)"); }
        } else {
            SWAITCNT("vmcnt(0)");
        }
        SBARRIER();    // joint: RAW(tile it landed) + WAR(tile it-1 readers done)
        if (it + 2 < NIT) {
            int b2 = cur + 2; if (b2 >= 3) b2 -= 3;
            STAGE((it + 2) << 5, b2);      // into tile it-1's buffer: WAR-safe
        }

        const u16* Ab = As[cur];
        const u16* Bb = Bs[cur];
        bf16x8 af[2];
        #pragma unroll
        for (int mt = 0; mt < 2; mt++) {
            int row = wm + mt * 16 + col;
            af[mt] = *(const bf16x8*)&Ab[row * 32 + ((quad ^ ((row >> 1) & 3)) * 8)];
        }
        #pragma unroll
        for (int nt = 0; nt < 18; nt++) {
            int row = nt * 16 + col;
            bf16x8 bfr = *(const bf16x8*)&Bb[row * 32 + ((quad ^ ((row >> 1) & 3)) * 8)];
            acc[0][nt] = mfma16(af[0], bfr, acc[0][nt]);
            acc[1][nt] = mfma16(af[1], bfr, acc[1][nt]);
        }

        cur = (cur == 2) ? 0 : cur + 1;
    }
    #undef STAGE

    // ---- q,k epilogue: direct scatter (32B-coalesced), unchanged ----
    #pragma unroll
    for (int mt = 0; mt < 2; mt++) {
        #pragma unroll
        for (int nt = 0; nt < 12; nt++) {
            const int sec = nt / 6;
            const int cc  = n0 + (nt - sec * 6) * 16 + col;   // 0..767
            const int h   = cc >> 6;
            const int d   = cc & 63;
            #pragma unroll
            for (int r = 0; r < 4; r++) {
                int m = m0 + wm + mt * 16 + quad * 4 + r;
                int b = m >> 10;
                int t = m & 1023;
                int bh = b * H_ + h;
                float v = acc[mt][nt][r] + bias[sec * C_ + cc];
                u16 bv = f2b(v);
                if (sec == 0) qo[((size_t)bh * T_ + t) * DK + d] = bv;
                else          ko[((size_t)bh * T_ + t) * DK + d] = bv;
            }
        }
    }

    // ---- v epilogue: LDS transpose -> coalesced bf16x8 stores ----
    // Safe to reuse Bs bytes [0, 26112): after the it=23 barrier every wave
    // reads only As[2]/Bs[2] (Bs[2] starts at byte 36864).
    // Write coverage: 4 waves (wm) x mt x quad x r tile t=0..127; 6 nt x col
    // tile ccl=0..95 — each cell exactly once.
    {
        u16* vlds = (u16*)Bs;                 // [96][136] stride: banks 2-way-free
        #pragma unroll
        for (int mt = 0; mt < 2; mt++) {
            #pragma unroll
            for (int nt = 12; nt < 18; nt++) {
                const int ccl = (nt - 12) * 16 + col;          // 0..95
                const float bv = bias[2 * C_ + n0 + ccl];
                const int t0  = wm + mt * 16 + quad * 4;       // 0..124, mult of 4
                bf16x4 pp;
                #pragma unroll
                for (int r = 0; r < 4; r++)
                    ((u16*)&pp)[r] = f2b(acc[mt][nt][r] + bv);
                *(bf16x4*)&vlds[ccl * 136 + t0] = pp;
            }
        }
        SWAITCNT("lgkmcnt(0)");   // ds_writes retired before cross-wave handoff
        SBARRIER();
        // Read coverage (R12 bugfix): 6 passes x 16 rows (row 0..95);
        // tch = (tid&15)*8 covers t = 0..127 in 8-elem steps. 16 consecutive
        // lanes store 256 contiguous bytes per row -> fully coalesced.
        const int bb  = m0 >> 10;
        const int m0t = m0 & 1023;
        #pragma unroll
        for (int g = 0; g < 6; g++) {
            const int row = g * 16 + (tid >> 4);               // 0..95
            const int tch = (tid & 15) * 8;                    // 0..120
            bf16x8 vv = *(const bf16x8*)&vlds[row * 136 + tch];
            *(bf16x8*)&vto[(size_t)(bb * C_ + n0 + row) * T_ + m0t + tch] = vv;
        }
    }
}

// ---------- out-proj GEMM: 128x96, BK=64, 2-buffer, single barrier/iter ----------
// R16: R5-proven structure ported; 512 blocks at 2/CU = one balanced round.
// Measured R8: total -3.1us. KEEP.
__global__ __launch_bounds__(256, 2)
void k_gemm_out(const u16* __restrict__ A, const u16* __restrict__ Bt,
                const float* __restrict__ bias, float* __restrict__ outf)
{
    const int K = C_, N = C_;
    __shared__ u16 As[2][2][128 * 32];   // [buf][sub]  2 x 16 KB
    __shared__ u16 Bs[2][2][96 * 32];    // [buf][sub]  2 x 12 KB  (56 KB total)
    const int tid  = threadIdx.x;
    const int lane = tid & 63;
    const int w    = tid >> 6;
    const int quad = lane >> 4;
    const int col  = lane & 15;

    const int id   = blockIdx.x;          // 0..511
    const int xcd  = id & 7;
    const int slot = id >> 3;             // 0..63
    const int m0   = (xcd * 8 + (slot & 7)) * 128;   // 64 m-tiles
    const int n0   = (slot >> 3) * 96;               // 8 n-tiles

    const int wm   = w * 32;              // 4 waves stacked in M

    f32x4 zero4 = {0.f, 0.f, 0.f, 0.f};
    f32x4 acc[2][6];
    #pragma unroll
    for (int i = 0; i < 2; i++)
        #pragma unroll
        for (int j = 0; j < 6; j++) acc[i][j] = zero4;

    const int sr  = tid >> 2;             // 0..63
    const int scc = ((tid & 3) ^ ((sr >> 1) & 3)) * 8;
    const u16* gA = A  + (size_t)(m0 + sr) * K + scc;
    const u16* gB = Bt + (size_t)(n0 + sr) * K + scc;

    const int NT64 = K >> 6;   // 12 K-tiles of 64

    #define SUB(kt, bufi, subi)                                                           \
        do {                                                                              \
            gl_lds16(gA + (kt),                  (char*)As[bufi][subi] + w * 1024);       \
            gl_lds16(gA + (size_t)64 * K + (kt), (char*)As[bufi][subi] + 4096 + w * 1024);\
            gl_lds16(gB + (kt),                  (char*)Bs[bufi][subi] + w * 1024);       \
            if (w < 2)                                                                    \
                gl_lds16(gB + (size_t)64 * K + (kt), (char*)Bs[bufi][subi] + 4096 + w * 1024);\
        } while (0)
    #define STAGE(t, bufi)  do { SUB(((t) << 6), bufi, 0); SUB(((t) << 6) + 32, bufi, 1); } while (0)

    STAGE(0, 0);
    for (int it = 0; it < NT64; ++it) {
        const int cur = it & 1;
        SWAITCNT("vmcnt(0)");   // drain own tile-it loads (issued iter it-1)
        SBARRIER();             // joint: RAW(tile it landed) + WAR(tile it-1 readers done)
        if (it + 1 < NT64)
            STAGE(it + 1, cur ^ 1);   // into tile it-1's buffer: WAR-safe

        #pragma unroll
        for (int kk = 0; kk < 2; ++kk) {
            const u16* Ab = As[cur][kk];
            const u16* Bb = Bs[cur][kk];
            bf16x8 af[2], bfr[6];
            #pragma unroll
            for (int mt = 0; mt < 2; mt++) {
                int row = wm + mt * 16 + col;
                af[mt] = *(const bf16x8*)&Ab[row * 32 + ((quad ^ ((row >> 1) & 3)) * 8)];
            }
            #pragma unroll
            for (int nt = 0; nt < 6; nt++) {
                int row = nt * 16 + col;
                bfr[nt] = *(const bf16x8*)&Bb[row * 32 + ((quad ^ ((row >> 1) & 3)) * 8)];
            }
            #pragma unroll
            for (int mt = 0; mt < 2; mt++)
                #pragma unroll
                for (int nt = 0; nt < 6; nt++)
                    acc[mt][nt] = mfma16(af[mt], bfr[nt], acc[mt][nt]);
        }
    }
    #undef STAGE
    #undef SUB

    #pragma unroll
    for (int mt = 0; mt < 2; mt++) {
        #pragma unroll
        for (int nt = 0; nt < 6; nt++) {
            #pragma unroll
            for (int r = 0; r < 4; r++) {
                int m = m0 + wm + mt * 16 + quad * 4 + r;
                int n = n0 + nt * 16 + col;
                outf[(size_t)m * N + n] = acc[mt][nt][r] + bias[n];
            }
        }
    }
}

// ---------- causal flash attention: R8 version (dist-1 dbuf, single barrier) ----------
// R18 lesson: L2-direct (no staging) regressed 68us — the gl_lds pipeline's
// decoupled issue/consume IS the value. R9 lesson: dist-2 at 2/CU = wash.
// This (dist-1, 2-buffer, 3/CU) is the best measured attn config.
#define PSTRIDE 72   // u16 elems; 144B rows

__device__ __forceinline__ bf16x8 ld_sw(const u16* base, int row, int half,
                                        int quad, int c7) {
    return *(const bf16x8*)(base + row * DK + (((half * 4 + quad) ^ c7) * 8));
}

template <bool MASK>
__device__ __forceinline__ void attn_chunk(
    const u16* Ks, const u16* Vs, __bf16* pbuf,
    const bf16x8 (&qf)[2][2], bf16x8 ones,
    int kv0, int qw, int quad, int col,
    f32x4 (&oacc)[2][4], f32x4 (&lacc)[2])
{
    const int c7 = col & 7;
    f32x4 zero4 = {0.f, 0.f, 0.f, 0.f};
    f32x4 st[2][4];
    #pragma unroll
    for (int g = 0; g < 4; g++) {
        bf16x8 klo = ld_sw(Ks, g * 16 + col, 0, quad, c7);
        bf16x8 khi = ld_sw(Ks, g * 16 + col, 1, quad, c7);
        st[0][g] = mfma16(khi, qf[0][1], mfma16(klo, qf[0][0], zero4));
        st[1][g] = mfma16(khi, qf[1][1], mfma16(klo, qf[1][0], zero4));
    }
    const float scl = 0.18033688f;   // log2(e)/8
    #pragma unroll
    for (int s = 0; s < 2; s++) {
        __bf16* pb = pbuf + s * 16 * PSTRIDE + col * PSTRIDE;
        #pragma unroll
        for (int g = 0; g < 4; g++) {
            bf16x4 pp;
            #pragma unroll
            for (int r = 0; r < 4; r++) {
                float p = __builtin_amdgcn_exp2f(st[s][g][r] * scl - 12.0f);
                if (MASK) {
                    int kv = kv0 + g * 16 + quad * 4 + r;
                    if (kv > qw + s * 16 + col) p = 0.f;
                }
                pp[r] = (__bf16)p;
            }
            *(bf16x4*)(pb + g * 16 + quad * 4) = pp;
        }
    }
    SWAITCNT("lgkmcnt(0)");   // wave-local LDS ordering for P round-trip
    bf16x8 pf[2][2];
    #pragma unroll
    for (int s = 0; s < 2; s++) {
        const __bf16* pb = pbuf + s * 16 * PSTRIDE + col * PSTRIDE;
        pf[s][0] = *(const bf16x8*)(pb + quad * 8);
        pf[s][1] = *(const bf16x8*)(pb + 32 + quad * 8);
        lacc[s] = mfma16(pf[s][1], ones, mfma16(pf[s][0], ones, lacc[s]));
    }
    #pragma unroll
    for (int dt = 0; dt < 4; dt++) {
        bf16x8 vlo = ld_sw(Vs, dt * 16 + col, 0, quad, c7);
        bf16x8 vhi = ld_sw(Vs, dt * 16 + col, 1, quad, c7);
        #pragma unroll
        for (int s = 0; s < 2; s++)
            oacc[s][dt] = mfma16(pf[s][1], vhi, mfma16(pf[s][0], vlo, oacc[s][dt]));
    }
}

__global__ __launch_bounds__(256, 3)
void k_attn(const u16* __restrict__ Q, const u16* __restrict__ Kf,
            const u16* __restrict__ Vt, u16* __restrict__ Of)
{
    __shared__ u16 Ks[2][64 * DK];
    __shared__ u16 Vs[2][64 * DK];
    __shared__ __bf16 Plds[4][32 * PSTRIDE];
    const int bh   = blockIdx.x;
    const int b    = bh / H_;
    const int h    = bh - b * H_;
    const int tid  = threadIdx.x;
    const int lane = tid & 63;
    const int w    = tid >> 6;
    const int quad = lane >> 4;
    const int col  = lane & 15;
    const int ty   = 7 - (int)blockIdx.y;
    const int nch  = 2 * ty + 2;
    const int qw   = ty * 128 + w * 32;
    __bf16* pbuf = Plds[w];

    const u16* Qb = Q  + (size_t)bh * T_ * DK;
    const u16* Kb = Kf + (size_t)bh * T_ * DK;
    const u16* Vb = Vt + (size_t)bh * DK * T_;

    int sG0 = tid, sG1 = 256 + tid;
    int sr0 = sG0 >> 3, sg0 = (sG0 & 7) ^ (sr0 & 7);
    int sr1 = sG1 >> 3, sg1 = (sG1 & 7) ^ (sr1 & 7);

    bf16x8 qf[2][2];
    #pragma unroll
    for (int s = 0; s < 2; s++) {
        const u16* qp = Qb + (size_t)(qw + s * 16 + col) * DK;
        qf[s][0] = *(const bf16x8*)(qp + quad * 8);
        qf[s][1] = *(const bf16x8*)(qp + 32 + quad * 8);
    }

    bf16x8 ones;
    #pragma unroll
    for (int i = 0; i < 8; i++) ((u16*)&ones)[i] = 0x3F80;

    f32x4 zero4 = {0.f, 0.f, 0.f, 0.f};
    f32x4 oacc[2][4];
    f32x4 lacc[2] = {zero4, zero4};
    #pragma unroll
    for (int s = 0; s < 2; s++)
        #pragma unroll
        for (int dt = 0; dt < 4; dt++) oacc[s][dt] = zero4;

    #define ASTAGE(c, bufi)                                                            \
        do {                                                                           \
            int kvs = (c) * 64;                                                        \
            gl_lds16(Kb + (size_t)(kvs + sr0) * DK + sg0 * 8, (char*)Ks[bufi] + w * 1024);        \
            gl_lds16(Kb + (size_t)(kvs + sr1) * DK + sg1 * 8, (char*)Ks[bufi] + 4096 + w * 1024); \
            gl_lds16(Vb + (size_t)sr0 * T_ + kvs + sg0 * 8,   (char*)Vs[bufi] + w * 1024);        \
            gl_lds16(Vb + (size_t)sr1 * T_ + kvs + sg1 * 8,   (char*)Vs[bufi] + 4096 + w * 1024); \
        } while (0)

    ASTAGE(0, 0);
    #pragma unroll 1
    for (int c = 0; c < nch; ++c) {
        const int cur = c & 1;
        SWAITCNT("vmcnt(0)");              // own chunk-c loads drained
        SBARRIER();                        // joint: chunk c landed + buf[!cur] readers done
        if (c + 1 < nch) {
            ASTAGE(c + 1, cur ^ 1);        // WAR-safe post-barrier
        }

        const int kv0 = c * 64;
        if (kv0 <= qw + 31) {
            if (kv0 + 63 <= qw)
                attn_chunk<false>(Ks[cur], Vs[cur], pbuf, qf, ones, kv0, qw, quad, col, oacc, lacc);
            else
                attn_chunk<true>(Ks[cur], Vs[cur], pbuf, qf, ones, kv0, qw, quad, col, oacc, lacc);
        }
    }
    #undef ASTAGE

    #pragma unroll
    for (int s = 0; s < 2; s++) {
        #pragma unroll
        for (int r = 0; r < 4; r++) {
            float inv = 1.f / lacc[s][r];
            int t = qw + s * 16 + quad * 4 + r;
            u16* op = Of + ((size_t)(b * T_ + t)) * C_ + h * DK;
            #pragma unroll
            for (int dt = 0; dt < 4; dt++) op[dt * 16 + col] = f2b(oacc[s][dt][r] * inv);
        }
    }
}

extern "C" void kernel_launch(void* const* d_in, const int* in_sizes, int n_in,
                              void* d_out, int out_size, void* d_ws, size_t ws_size,
                              hipStream_t stream) {
    const float* x    = (const float*)d_in[0];
    const float* Wqkv = (const float*)d_in[1];
    const float* bqkv = (const float*)d_in[2];
    const float* Wout = (const float*)d_in[3];
    const float* bout = (const float*)d_in[4];
    float* out = (float*)d_out;

    char* ws = (char*)d_ws;
    u16* xb    = (u16*)(ws);                    // 8192*768     bf16 = 12.0 MiB
    u16* wqkvT = (u16*)(ws + 12582912);         // [2304,768]   bf16
    u16* woutT = (u16*)(ws + 16121856);         // [768,768]    bf16
    u16* qw    = (u16*)(ws + 17301504);         // [96,1024,64] bf16
    u16* kw    = (u16*)(ws + 29884416);         // [96,1024,64] bf16
    u16* vtw   = (u16*)(ws + 42467328);         // [96,64,1024] bf16
    u16* aw    = (u16*)(ws + 55050240);         // [8192,768]   bf16  (end ~67.6 MB)

    k_prep<<<8448, 256, 0, stream>>>(x, xb, Wqkv, wqkvT, Wout, woutT);

    k_gemm_qkv<<<dim3(8, BT / 128), 256, 0, stream>>>(
        xb, wqkvT, bqkv, qw, kw, vtw);

    k_attn<<<dim3(B_ * H_, 8), 256, 0, stream>>>(qw, kw, vtw, aw);

    k_gemm_out<<<512, 256, 0, stream>>>(aw, woutT, bout, out);
}

// Round 14
// 172.162 us; speedup vs baseline: 1.2278x; 1.0047x over previous
//
#include <hip/hip_runtime.h>
#include <stdint.h>

#define B_ 8
#define T_ 1024
#define C_ 768
#define H_ 12
#define DK 64
#define BT (B_*T_)      // 8192
#define NQKV (3*C_)     // 2304

typedef unsigned short u16;
typedef __bf16 bf16x8 __attribute__((ext_vector_type(8)));
typedef __bf16 bf16x4 __attribute__((ext_vector_type(4)));
typedef float  f32x4  __attribute__((ext_vector_type(4)));

typedef const __attribute__((address_space(1))) void gvoid_t;
typedef __attribute__((address_space(3))) void lvoid_t;

// Raw s_barrier is NOT a compiler fence (LLVM IntrNoMem) — caused R6's replay
// race. asm volatile + "memory" clobber = compiler-only fence, zero extra
// instructions, preserves fine-grained vmcnt pipelining.
#define SBARRIER()  asm volatile("s_barrier" ::: "memory")
#define SWAITCNT(s) asm volatile("s_waitcnt " s ::: "memory")

__device__ __forceinline__ void gl_lds16(const void* g, void* l) {
    __builtin_amdgcn_global_load_lds((gvoid_t*)g, (lvoid_t*)l, 16, 0, 0);
}

__device__ __forceinline__ u16 f2b(float f) {
    union { float f; unsigned int u; } v; v.f = f;
    unsigned int u = v.u;
    return (u16)((u + 0x7fffu + ((u >> 16) & 1u)) >> 16);
}

__device__ __forceinline__ f32x4 mfma16(bf16x8 a, bf16x8 b, f32x4 c) {
    return __builtin_amdgcn_mfma_f32_16x16x32_bf16(a, b, c, 0, 0, 0);
}

// ---------- merged prep: convert x + transpose both W (one launch) ----------
__global__ __launch_bounds__(256)
void k_prep(const float* __restrict__ x, u16* __restrict__ xb,
            const float* __restrict__ wqkv, u16* __restrict__ wqkvT,
            const float* __restrict__ wout, u16* __restrict__ woutT)
{
    __shared__ u16 tile[32][34];
    const int bid = blockIdx.x;
    const int tid = threadIdx.x;
    if (bid < 6144) {
        int i = bid * 256 + tid;
        float4 f = ((const float4*)x)[i];
        uint2 o;
        o.x = (unsigned)f2b(f.x) | ((unsigned)f2b(f.y) << 16);
        o.y = (unsigned)f2b(f.z) | ((unsigned)f2b(f.w) << 16);
        ((uint2*)xb)[i] = o;
        return;
    }
    const float* w; u16* wt; int K, N, n0, k0;
    if (bid < 6144 + 1728) {
        int idx = bid - 6144;
        w = wqkv; wt = wqkvT; K = C_; N = NQKV;
        n0 = (idx % 72) * 32; k0 = (idx / 72) * 32;
    } else {
        int idx = bid - 7872;
        w = wout; wt = woutT; K = C_; N = C_;
        n0 = (idx % 24) * 32; k0 = (idx / 24) * 32;
    }
    const int tx = tid & 31, ty = tid >> 5;   // 32 x 8
    #pragma unroll
    for (int i = 0; i < 4; i++)
        tile[ty + i * 8][tx] = f2b(w[(size_t)(k0 + ty + i * 8) * N + n0 + tx]);
    __syncthreads();
    #pragma unroll
    for (int i = 0; i < 4; i++)
        wt[(size_t)(n0 + ty + i * 8) * K + k0 + tx] = tile[tx][ty + i * 8];
}

// ---------- QKV GEMM: 128 x (3x96) A-reuse tile, BK=32, 3-stage dist-2 ----------
// R15/R7: A-tile staged once for all three qkv sections (3x output area);
// 512 blocks = one round at 2/CU. Measured 51.7us. BEST — kept verbatim.
// R20/R21 (v-epilogue LDS transpose): NEUTRAL on timing (write path not on
// the critical path; qkv is staging-throughput-bound) and added 147K bank
// conflicts — REVERTED to the direct scatter.
__global__ __launch_bounds__(256, 2)
void k_gemm_qkv(const u16* __restrict__ A, const u16* __restrict__ Bt,
                const float* __restrict__ bias,
                u16* __restrict__ qo, u16* __restrict__ ko, u16* __restrict__ vto)
{
    const int K = C_;
    __shared__ u16 As[3][128 * 32];   // 3 x 8 KB
    __shared__ u16 Bs[3][288 * 32];   // 3 x 18 KB  (78 KB total -> 2 blocks/CU)
    const int tid  = threadIdx.x;
    const int lane = tid & 63;
    const int w    = tid >> 6;
    const int quad = lane >> 4;
    const int col  = lane & 15;

    const int id   = blockIdx.x + gridDim.x * blockIdx.y;  // grid (8, 64) = 512
    const int xcd  = id & 7;
    const int slot = id >> 3;             // 0..63
    const int m0   = (xcd * 8 + (slot & 7)) * 128;   // 64 m-tiles
    const int n0   = (slot >> 3) * 96;               // 8 n-groups (96 cols/section)

    const int wm   = w * 32;              // 4 waves stacked in M

    f32x4 zero4 = {0.f, 0.f, 0.f, 0.f};
    f32x4 acc[2][18];
    #pragma unroll
    for (int i = 0; i < 2; i++)
        #pragma unroll
        for (int j = 0; j < 18; j++) acc[i][j] = zero4;

    const int sr  = tid >> 2;             // 0..63
    const int scc = ((tid & 3) ^ ((sr >> 1) & 3)) * 8;
    const u16* gA = A  + (size_t)(m0 + sr) * K + scc;
    const u16* gB = Bt + (size_t)(n0 + sr) * K + scc;   // +s*768*K per section

    const int NIT = K >> 5;   // 24

    // A: rows 0-63 + 64-127 (2 all-wave loads). B per section s (LDS rows
    // s*96..s*96+95): rows 0-63 all waves; rows 64-95 waves 0,1 (their sr in
    // 0..31 -> gB + 64*K). Section LDS base = s*96*32*2 = s*6144 bytes.
    #define STAGE(kt, bufi)                                                               \
        do {                                                                              \
            gl_lds16(gA + (kt),                  (char*)As[bufi] + w * 1024);             \
            gl_lds16(gA + (size_t)64 * K + (kt), (char*)As[bufi] + 4096 + w * 1024);      \
            _Pragma("unroll")                                                             \
            for (int s = 0; s < 3; s++) {                                                 \
                const u16* gBs = gB + (size_t)(s * C_) * K;                               \
                gl_lds16(gBs + (kt), (char*)Bs[bufi] + s * 6144 + w * 1024);              \
                if (w < 2)                                                                \
                    gl_lds16(gBs + (size_t)64 * K + (kt),                                 \
                             (char*)Bs[bufi] + s * 6144 + 4096 + w * 1024);               \
            }                                                                             \
        } while (0)

    STAGE(0, 0);
    STAGE(32, 1);
    int cur = 0;
    for (int it = 0; it < NIT; ++it) {
        // drain OWN tile-it loads (issued at it-2); tile it+1's stay in flight
        if (it + 1 < NIT) {
            if (w < 2) { SWAITCNT("vmcnt(8)"); } else { SWAITCNT("vmcnt(5)"); }
        } else {
            SWAITCNT("vmcnt(0)");
        }
        SBARRIER();    // joint: RAW(tile it landed) + WAR(tile it-1 readers done)
        if (it + 2 < NIT) {
            int b2 = cur + 2; if (b2 >= 3) b2 -= 3;
            STAGE((it + 2) << 5, b2);      // into tile it-1's buffer: WAR-safe
        }

        const u16* Ab = As[cur];
        const u16* Bb = Bs[cur];
        bf16x8 af[2];
        #pragma unroll
        for (int mt = 0; mt < 2; mt++) {
            int row = wm + mt * 16 + col;
            af[mt] = *(const bf16x8*)&Ab[row * 32 + ((quad ^ ((row >> 1) & 3)) * 8)];
        }
        #pragma unroll
        for (int nt = 0; nt < 18; nt++) {
            int row = nt * 16 + col;
            bf16x8 bfr = *(const bf16x8*)&Bb[row * 32 + ((quad ^ ((row >> 1) & 3)) * 8)];
            acc[0][nt] = mfma16(af[0], bfr, acc[0][nt]);
            acc[1][nt] = mfma16(af[1], bfr, acc[1][nt]);
        }

        cur = (cur == 2) ? 0 : cur + 1;
    }
    #undef STAGE

    // epilogue: nt 0-5 -> q, 6-11 -> k, 12-17 -> v (96 cols each, 16-aligned)
    #pragma unroll
    for (int mt = 0; mt < 2; mt++) {
        #pragma unroll
        for (int nt = 0; nt < 18; nt++) {
            const int sec = nt / 6;
            const int cc  = n0 + (nt - sec * 6) * 16 + col;   // 0..767
            const int h   = cc >> 6;
            const int d   = cc & 63;
            #pragma unroll
            for (int r = 0; r < 4; r++) {
                int m = m0 + wm + mt * 16 + quad * 4 + r;
                int b = m >> 10;
                int t = m & 1023;
                int bh = b * H_ + h;
                float v = acc[mt][nt][r] + bias[sec * C_ + cc];
                u16 bv = f2b(v);
                if (sec == 0)      qo [((size_t)bh * T_ + t) * DK + d] = bv;
                else if (sec == 1) ko [((size_t)bh * T_ + t) * DK + d] = bv;
                else               vto[((size_t)bh * DK + d) * T_ + t] = bv;
            }
        }
    }
}

// ---------- out-proj GEMM: 128x96, BK=64, 2-buffer, single barrier/iter ----------
// R16: R5-proven structure ported; 512 blocks at 2/CU = one balanced round.
// Measured R8: total -3.1us. KEEP.
__global__ __launch_bounds__(256, 2)
void k_gemm_out(const u16* __restrict__ A, const u16* __restrict__ Bt,
                const float* __restrict__ bias, float* __restrict__ outf)
{
    const int K = C_, N = C_;
    __shared__ u16 As[2][2][128 * 32];   // [buf][sub]  2 x 16 KB
    __shared__ u16 Bs[2][2][96 * 32];    // [buf][sub]  2 x 12 KB  (56 KB total)
    const int tid  = threadIdx.x;
    const int lane = tid & 63;
    const int w    = tid >> 6;
    const int quad = lane >> 4;
    const int col  = lane & 15;

    const int id   = blockIdx.x;          // 0..511
    const int xcd  = id & 7;
    const int slot = id >> 3;             // 0..63
    const int m0   = (xcd * 8 + (slot & 7)) * 128;   // 64 m-tiles
    const int n0   = (slot >> 3) * 96;               // 8 n-tiles

    const int wm   = w * 32;              // 4 waves stacked in M

    f32x4 zero4 = {0.f, 0.f, 0.f, 0.f};
    f32x4 acc[2][6];
    #pragma unroll
    for (int i = 0; i < 2; i++)
        #pragma unroll
        for (int j = 0; j < 6; j++) acc[i][j] = zero4;

    const int sr  = tid >> 2;             // 0..63
    const int scc = ((tid & 3) ^ ((sr >> 1) & 3)) * 8;
    const u16* gA = A  + (size_t)(m0 + sr) * K + scc;
    const u16* gB = Bt + (size_t)(n0 + sr) * K + scc;

    const int NT64 = K >> 6;   // 12 K-tiles of 64

    #define SUB(kt, bufi, subi)                                                           \
        do {                                                                              \
            gl_lds16(gA + (kt),                  (char*)As[bufi][subi] + w * 1024);       \
            gl_lds16(gA + (size_t)64 * K + (kt), (char*)As[bufi][subi] + 4096 + w * 1024);\
            gl_lds16(gB + (kt),                  (char*)Bs[bufi][subi] + w * 1024);       \
            if (w < 2)                                                                    \
                gl_lds16(gB + (size_t)64 * K + (kt), (char*)Bs[bufi][subi] + 4096 + w * 1024);\
        } while (0)
    #define STAGE(t, bufi)  do { SUB(((t) << 6), bufi, 0); SUB(((t) << 6) + 32, bufi, 1); } while (0)

    STAGE(0, 0);
    for (int it = 0; it < NT64; ++it) {
        const int cur = it & 1;
        SWAITCNT("vmcnt(0)");   // drain own tile-it loads (issued iter it-1)
        SBARRIER();             // joint: RAW(tile it landed) + WAR(tile it-1 readers done)
        if (it + 1 < NT64)
            STAGE(it + 1, cur ^ 1);   // into tile it-1's buffer: WAR-safe

        #pragma unroll
        for (int kk = 0; kk < 2; ++kk) {
            const u16* Ab = As[cur][kk];
            const u16* Bb = Bs[cur][kk];
            bf16x8 af[2], bfr[6];
            #pragma unroll
            for (int mt = 0; mt < 2; mt++) {
                int row = wm + mt * 16 + col;
                af[mt] = *(const bf16x8*)&Ab[row * 32 + ((quad ^ ((row >> 1) & 3)) * 8)];
            }
            #pragma unroll
            for (int nt = 0; nt < 6; nt++) {
                int row = nt * 16 + col;
                bfr[nt] = *(const bf16x8*)&Bb[row * 32 + ((quad ^ ((row >> 1) & 3)) * 8)];
            }
            #pragma unroll
            for (int mt = 0; mt < 2; mt++)
                #pragma unroll
                for (int nt = 0; nt < 6; nt++)
                    acc[mt][nt] = mfma16(af[mt], bfr[nt], acc[mt][nt]);
        }
    }
    #undef STAGE
    #undef SUB

    #pragma unroll
    for (int mt = 0; mt < 2; mt++) {
        #pragma unroll
        for (int nt = 0; nt < 6; nt++) {
            #pragma unroll
            for (int r = 0; r < 4; r++) {
                int m = m0 + wm + mt * 16 + quad * 4 + r;
                int n = n0 + nt * 16 + col;
                outf[(size_t)m * N + n] = acc[mt][nt][r] + bias[n];
            }
        }
    }
}

// ---------- causal flash attention: R8 structure + T5 setprio on MFMA ----------
// R18: L2-direct regressed (gl_lds pipelining is the value). R9: dist-2 at
// 2/CU = wash. This dist-1/2-buffer/3-blocks-per-CU config is the measured
// best. R22 (this round): T5 s_setprio(1) around the QK^T and PV MFMA
// clusters — 3 independent blocks/CU at different phases = m191's positive
// regime (wave role diversity), unlike m190's lockstep-GEMM null.
#define PSTRIDE 72   // u16 elems; 144B rows

__device__ __forceinline__ bf16x8 ld_sw(const u16* base, int row, int half,
                                        int quad, int c7) {
    return *(const bf16x8*)(base + row * DK + (((half * 4 + quad) ^ c7) * 8));
}

template <bool MASK>
__device__ __forceinline__ void attn_chunk(
    const u16* Ks, const u16* Vs, __bf16* pbuf,
    const bf16x8 (&qf)[2][2], bf16x8 ones,
    int kv0, int qw, int quad, int col,
    f32x4 (&oacc)[2][4], f32x4 (&lacc)[2])
{
    const int c7 = col & 7;
    f32x4 zero4 = {0.f, 0.f, 0.f, 0.f};
    f32x4 st[2][4];
    __builtin_amdgcn_s_setprio(1);
    #pragma unroll
    for (int g = 0; g < 4; g++) {
        bf16x8 klo = ld_sw(Ks, g * 16 + col, 0, quad, c7);
        bf16x8 khi = ld_sw(Ks, g * 16 + col, 1, quad, c7);
        st[0][g] = mfma16(khi, qf[0][1], mfma16(klo, qf[0][0], zero4));
        st[1][g] = mfma16(khi, qf[1][1], mfma16(klo, qf[1][0], zero4));
    }
    __builtin_amdgcn_s_setprio(0);
    const float scl = 0.18033688f;   // log2(e)/8
    #pragma unroll
    for (int s = 0; s < 2; s++) {
        __bf16* pb = pbuf + s * 16 * PSTRIDE + col * PSTRIDE;
        #pragma unroll
        for (int g = 0; g < 4; g++) {
            bf16x4 pp;
            #pragma unroll
            for (int r = 0; r < 4; r++) {
                float p = __builtin_amdgcn_exp2f(st[s][g][r] * scl - 12.0f);
                if (MASK) {
                    int kv = kv0 + g * 16 + quad * 4 + r;
                    if (kv > qw + s * 16 + col) p = 0.f;
                }
                pp[r] = (__bf16)p;
            }
            *(bf16x4*)(pb + g * 16 + quad * 4) = pp;
        }
    }
    SWAITCNT("lgkmcnt(0)");   // wave-local LDS ordering for P round-trip
    bf16x8 pf[2][2];
    __builtin_amdgcn_s_setprio(1);
    #pragma unroll
    for (int s = 0; s < 2; s++) {
        const __bf16* pb = pbuf + s * 16 * PSTRIDE + col * PSTRIDE;
        pf[s][0] = *(const bf16x8*)(pb + quad * 8);
        pf[s][1] = *(const bf16x8*)(pb + 32 + quad * 8);
        lacc[s] = mfma16(pf[s][1], ones, mfma16(pf[s][0], ones, lacc[s]));
    }
    #pragma unroll
    for (int dt = 0; dt < 4; dt++) {
        bf16x8 vlo = ld_sw(Vs, dt * 16 + col, 0, quad, c7);
        bf16x8 vhi = ld_sw(Vs, dt * 16 + col, 1, quad, c7);
        #pragma unroll
        for (int s = 0; s < 2; s++)
            oacc[s][dt] = mfma16(pf[s][1], vhi, mfma16(pf[s][0], vlo, oacc[s][dt]));
    }
    __builtin_amdgcn_s_setprio(0);
}

__global__ __launch_bounds__(256, 3)
void k_attn(const u16* __restrict__ Q, const u16* __restrict__ Kf,
            const u16* __restrict__ Vt, u16* __restrict__ Of)
{
    __shared__ u16 Ks[2][64 * DK];
    __shared__ u16 Vs[2][64 * DK];
    __shared__ __bf16 Plds[4][32 * PSTRIDE];
    const int bh   = blockIdx.x;
    const int b    = bh / H_;
    const int h    = bh - b * H_;
    const int tid  = threadIdx.x;
    const int lane = tid & 63;
    const int w    = tid >> 6;
    const int quad = lane >> 4;
    const int col  = lane & 15;
    const int ty   = 7 - (int)blockIdx.y;
    const int nch  = 2 * ty + 2;
    const int qw   = ty * 128 + w * 32;
    __bf16* pbuf = Plds[w];

    const u16* Qb = Q  + (size_t)bh * T_ * DK;
    const u16* Kb = Kf + (size_t)bh * T_ * DK;
    const u16* Vb = Vt + (size_t)bh * DK * T_;

    int sG0 = tid, sG1 = 256 + tid;
    int sr0 = sG0 >> 3, sg0 = (sG0 & 7) ^ (sr0 & 7);
    int sr1 = sG1 >> 3, sg1 = (sG1 & 7) ^ (sr1 & 7);

    bf16x8 qf[2][2];
    #pragma unroll
    for (int s = 0; s < 2; s++) {
        const u16* qp = Qb + (size_t)(qw + s * 16 + col) * DK;
        qf[s][0] = *(const bf16x8*)(qp + quad * 8);
        qf[s][1] = *(const bf16x8*)(qp + 32 + quad * 8);
    }

    bf16x8 ones;
    #pragma unroll
    for (int i = 0; i < 8; i++) ((u16*)&ones)[i] = 0x3F80;

    f32x4 zero4 = {0.f, 0.f, 0.f, 0.f};
    f32x4 oacc[2][4];
    f32x4 lacc[2] = {zero4, zero4};
    #pragma unroll
    for (int s = 0; s < 2; s++)
        #pragma unroll
        for (int dt = 0; dt < 4; dt++) oacc[s][dt] = zero4;

    #define ASTAGE(c, bufi)                                                            \
        do {                                                                           \
            int kvs = (c) * 64;                                                        \
            gl_lds16(Kb + (size_t)(kvs + sr0) * DK + sg0 * 8, (char*)Ks[bufi] + w * 1024);        \
            gl_lds16(Kb + (size_t)(kvs + sr1) * DK + sg1 * 8, (char*)Ks[bufi] + 4096 + w * 1024); \
            gl_lds16(Vb + (size_t)sr0 * T_ + kvs + sg0 * 8,   (char*)Vs[bufi] + w * 1024);        \
            gl_lds16(Vb + (size_t)sr1 * T_ + kvs + sg1 * 8,   (char*)Vs[bufi] + 4096 + w * 1024); \
        } while (0)

    ASTAGE(0, 0);
    #pragma unroll 1
    for (int c = 0; c < nch; ++c) {
        const int cur = c & 1;
        SWAITCNT("vmcnt(0)");              // own chunk-c loads drained
        SBARRIER();                        // joint: chunk c landed + buf[!cur] readers done
        if (c + 1 < nch) {
            ASTAGE(c + 1, cur ^ 1);        // WAR-safe post-barrier
        }

        const int kv0 = c * 64;
        if (kv0 <= qw + 31) {
            if (kv0 + 63 <= qw)
                attn_chunk<false>(Ks[cur], Vs[cur], pbuf, qf, ones, kv0, qw, quad, col, oacc, lacc);
            else
                attn_chunk<true>(Ks[cur], Vs[cur], pbuf, qf, ones, kv0, qw, quad, col, oacc, lacc);
        }
    }
    #undef ASTAGE

    #pragma unroll
    for (int s = 0; s < 2; s++) {
        #pragma unroll
        for (int r = 0; r < 4; r++) {
            float inv = 1.f / lacc[s][r];
            int t = qw + s * 16 + quad * 4 + r;
            u16* op = Of + ((size_t)(b * T_ + t)) * C_ + h * DK;
            #pragma unroll
            for (int dt = 0; dt < 4; dt++) op[dt * 16 + col] = f2b(oacc[s][dt][r] * inv);
        }
    }
}

extern "C" void kernel_launch(void* const* d_in, const int* in_sizes, int n_in,
                              void* d_out, int out_size, void* d_ws, size_t ws_size,
                              hipStream_t stream) {
    const float* x    = (const float*)d_in[0];
    const float* Wqkv = (const float*)d_in[1];
    const float* bqkv = (const float*)d_in[2];
    const float* Wout = (const float*)d_in[3];
    const float* bout = (const float*)d_in[4];
    float* out = (float*)d_out;

    char* ws = (char*)d_ws;
    u16* xb    = (u16*)(ws);                    // 8192*768     bf16 = 12.0 MiB
    u16* wqkvT = (u16*)(ws + 12582912);         // [2304,768]   bf16
    u16* woutT = (u16*)(ws + 16121856);         // [768,768]    bf16
    u16* qw    = (u16*)(ws + 17301504);         // [96,1024,64] bf16
    u16* kw    = (u16*)(ws + 29884416);         // [96,1024,64] bf16
    u16* vtw   = (u16*)(ws + 42467328);         // [96,64,1024] bf16
    u16* aw    = (u16*)(ws + 55050240);         // [8192,768]   bf16  (end ~67.6 MB)

    k_prep<<<8448, 256, 0, stream>>>(x, xb, Wqkv, wqkvT, Wout, woutT);

    k_gemm_qkv<<<dim3(8, BT / 128), 256, 0, stream>>>(
        xb, wqkvT, bqkv, qw, kw, vtw);

    k_attn<<<dim3(B_ * H_, 8), 256, 0, stream>>>(qw, kw, vtw, aw);

    k_gemm_out<<<512, 256, 0, stream>>>(aw, woutT, bout, out);
}